// Round 16
// baseline (55.622 us; speedup 1.0000x reference)
//
#include <hip/hip_runtime.h>
#include <math.h>

// LinearGating: B=4,S=4096,D=2048,E=64,K=2 -> N=16384 rows
// out (flat f32): [weights N*64][indices N*2 (as float)][logits N*64][probs N*64]
//
// fp16 split-3 MFMA GEMM: C[N x 128] = X[N x 2048] @ [Wg|Wn]
//   x = h + d, w = H + D;  acc1 += h*H ; acc2 += h*(D*2^6) + (d*2^6)*H
//   C = acc1 + acc2 * 2^-6
// R16 = R15 (unpinned, all-reg VMEM, compiler-counted waitcnts) with TWO
// segments per barrier: 16 barriers instead of 32. Bufs {0,1} consumed while
// {2,3} written, and vice versa. A regs depth-4 (slack 1 period), B 2 named
// sets reloaded immediately after use (slack 1 period >> L2 latency).

typedef _Float16 f16;
typedef f16  f16x4  __attribute__((ext_vector_type(4)));
typedef f16  f16x8  __attribute__((ext_vector_type(8)));
typedef float f32x16 __attribute__((ext_vector_type(16)));

constexpr int NROWS = 16384;
constexpr int DDIM  = 2048;
constexpr int NE    = 64;
constexpr int BM    = 32;
constexpr int KI    = 32;                 // k per segment per half
constexpr float NSCALE = 1.0f / 4096.0f;

// LDS: A f16 blobs [0,32K): buf(4) x half(2) x s(2) x v(2) x 1KB
//      merge mg [32K,48K); lgf reuses [0,16896) after k-loop
__device__ __forceinline__ int a_off(int buf, int h, int s, int v) {
    return (((buf * 2 + h) * 2 + s) * 2 + v) * 1024;
}

__device__ __forceinline__ float softplus_f(float x) {
    return fmaxf(x, 0.0f) + log1pf(expf(-fabsf(x)));
}

// ---------------- W prep: fragment-ordered fp16 {H, D*2^6} ----------------
// blob(S 0..127, f 0..3, v 0..1): lane l, elem j = Wcat[S*16+(l>>5)*8+j][f*32+(l&31)]
__global__ __launch_bounds__(256) void wprep_kernel(
    const float* __restrict__ Wg, const float* __restrict__ Wn,
    f16* __restrict__ ws)
{
    int t = blockIdx.x * 256 + threadIdx.x;    // 0..32767
    int S = t >> 8;
    int f = (t >> 6) & 3;
    int l = t & 63;
    int k0  = S * 16 + (l >> 5) * 8;
    int col = f * 32 + (l & 31);
    const float* src = (col < NE) ? (Wg + col) : (Wn + col - NE);
    f16x8 hp, lp;
    #pragma unroll
    for (int j = 0; j < 8; ++j) {
        float w  = src[(size_t)(k0 + j) * NE];
        f16 h    = (f16)w;
        float hf = (float)h;
        hp[j] = h;
        lp[j] = (f16)((w - hf) * 64.0f);
    }
    size_t base = (size_t)(S * 4 + f) * 1024;   // f16 units
    *(f16x8*)(ws + base + l * 8)       = hp;
    *(f16x8*)(ws + base + 512 + l * 8) = lp;
}

// ---------------- main fused kernel ----------------
__global__ __launch_bounds__(512, 4) void gemm_gating(
    const float* __restrict__ x, const f16* __restrict__ wfrag,
    const float* __restrict__ noise,
    float* __restrict__ out_w, float* __restrict__ out_idx,
    float* __restrict__ out_logits, float* __restrict__ out_probs)
{
    __shared__ __align__(16) char smem[49152];
    const int tid = threadIdx.x;
    const int l   = tid & 63;
    const int w   = tid >> 6;      // 0..7
    const int h   = w >> 2;        // compute: k-half
    const int f   = w & 3;         // compute: col quad (cols f*32..+31)
    const int row0 = blockIdx.x * BM;

    f32x16 acc1, acc2;
    #pragma unroll
    for (int r = 0; r < 16; ++r) { acc1[r] = 0.0f; acc2[r] = 0.0f; }

    // --- A staging role: wave w owns (h_s = w>>2, s_s = (w>>1)&1, j4 = w&1) ---
    const int h_s = w >> 2, s_s = (w >> 1) & 1, j4 = w & 1;
    const float* aSrc = x + (size_t)(row0 + (l & 31)) * DDIM
                          + h_s * 1024 + s_s * 16 + (l >> 5) * 8 + j4 * 4;
    auto loadA = [&](int t) -> float4 {
        return *(const float4*)(aSrc + (size_t)t * KI);
    };
    auto cvtWrite = [&](float4 xv, int buf) {   // buf is compile-time static
        float xs[4] = {xv.x, xv.y, xv.z, xv.w};
        f16x4 hi, lo;
        #pragma unroll
        for (int j = 0; j < 4; ++j) {
            f16 hh   = (f16)xs[j];
            float hf = (float)hh;
            hi[j] = hh;
            lo[j] = (f16)((xs[j] - hf) * 64.0f);
        }
        *(f16x4*)(smem + a_off(buf, h_s, s_s, 0) + l * 16 + j4 * 8) = hi;
        *(f16x4*)(smem + a_off(buf, h_s, s_s, 1) + l * 16 + j4 * 8) = lo;
    };

    // --- B: wave-private, global->reg. Slice S = h*64 + t*2 + s ---
    const f16* bBase = wfrag + (size_t)f * 1024 + l * 8;
#define LOADB(t, H0, L0, H1, L1) do {                                       \
        const f16* _p = bBase + (size_t)(h * 64 + (t) * 2) * 4096;          \
        H0 = *(const f16x8*)_p;          L0 = *(const f16x8*)(_p + 512);    \
        H1 = *(const f16x8*)(_p + 4096); L1 = *(const f16x8*)(_p + 4608);   \
    } while (0)

    auto compute = [&](int buf, f16x8 Bh0, f16x8 Bl0, f16x8 Bh1, f16x8 Bl1) {
        #pragma unroll
        for (int s = 0; s < 2; ++s) {
            f16x8 Ah = *(const f16x8*)(smem + a_off(buf, h, s, 0) + l * 16);
            f16x8 Al = *(const f16x8*)(smem + a_off(buf, h, s, 1) + l * 16);
            f16x8 Bh = s ? Bh1 : Bh0;
            f16x8 Bl = s ? Bl1 : Bl0;
            acc1 = __builtin_amdgcn_mfma_f32_32x32x16_f16(Ah, Bh, acc1, 0, 0, 0);
            acc2 = __builtin_amdgcn_mfma_f32_32x32x16_f16(Ah, Bl, acc2, 0, 0, 0);
            acc2 = __builtin_amdgcn_mfma_f32_32x32x16_f16(Al, Bh, acc2, 0, 0, 0);
        }
    };

    float4 a0, a1, a2, a3;
    f16x8 b0h0, b0l0, b0h1, b0l1;   // B set 0 (even segs)
    f16x8 b1h0, b1l0, b1h1, b1l1;   // B set 1 (odd segs)

    // -------- prologue: A(0..3) regs, B(0),B(1) regs, bufs 0,1 written --------
    a0 = loadA(0); a1 = loadA(1); a2 = loadA(2); a3 = loadA(3);
    LOADB(0, b0h0, b0l0, b0h1, b0l1);
    LOADB(1, b1h0, b1l0, b1h1, b1l1);
    cvtWrite(a0, 0);
    cvtWrite(a1, 1);
    __syncthreads();

    // -------- main loop: 8 trips x 2 super-segs (2 segs per barrier) --------
    for (int tb = 0; tb < 32; tb += 4) {
        // super-seg A: segs tb, tb+1 (bufs 0,1)
        compute(0, b0h0, b0l0, b0h1, b0l1);
        compute(1, b1h0, b1l0, b1h1, b1l1);
        if (tb + 4 < 32) { a0 = loadA(tb + 4); a1 = loadA(tb + 5); }
        if (tb + 2 < 32) {
            LOADB(tb + 2, b0h0, b0l0, b0h1, b0l1);
            LOADB(tb + 3, b1h0, b1l0, b1h1, b1l1);
        }
        cvtWrite(a2, 2);                       // seg tb+2 -> buf2
        cvtWrite(a3, 3);                       // seg tb+3 -> buf3
        __syncthreads();

        // super-seg B: segs tb+2, tb+3 (bufs 2,3)
        compute(2, b0h0, b0l0, b0h1, b0l1);
        compute(3, b1h0, b1l0, b1h1, b1l1);
        if (tb + 6 < 32) { a2 = loadA(tb + 6); a3 = loadA(tb + 7); }
        if (tb + 4 < 32) {
            LOADB(tb + 4, b0h0, b0l0, b0h1, b0l1);
            LOADB(tb + 5, b1h0, b1l0, b1h1, b1l1);
            cvtWrite(a0, 0);                   // seg tb+4 -> buf0
            cvtWrite(a1, 1);                   // seg tb+5 -> buf1
        }
        __syncthreads();
    }
#undef LOADB

    // ---- merge K-halves: h=1 waves write partial, h=0 adds ----
    float* mg = (float*)(smem + 32768);    // [32][128]
    if (h == 1) {
        #pragma unroll
        for (int r = 0; r < 16; ++r) {
            float cv = fmaf(acc2[r], 0.015625f, acc1[r]);
            int row = (r & 3) + 8 * (r >> 2) + 4 * (l >> 5);
            int col = f * 32 + (l & 31);
            mg[row * 128 + col] = cv;
        }
    }
    __syncthreads();

    float* lgf = (float*)smem;             // [32][132]
    if (h == 0) {
        #pragma unroll
        for (int r = 0; r < 16; ++r) {
            float cv = fmaf(acc2[r], 0.015625f, acc1[r]);
            int row = (r & 3) + 8 * (r >> 2) + 4 * (l >> 5);
            int col = f * 32 + (l & 31);
            lgf[row * 132 + col] = cv + mg[row * 128 + col];
        }
    }
    __syncthreads();

    // ---- phase1: noise injection; 512 thr = 32 rows x 16 float4-chunks ----
    {
        const int pr = tid & 31;           // row
        const int c4 = tid >> 5;           // float4 chunk 0..15
        const int n1 = row0 + pr;
        float4 G  = *(const float4*)(lgf + pr * 132 + c4 * 4);
        float4 NL = *(const float4*)(lgf + pr * 132 + 64 + c4 * 4);
        float4 NZ = *(const float4*)(noise + (size_t)n1 * NE + c4 * 4);
        G.x += NZ.x * softplus_f(NL.x) * NSCALE;
        G.y += NZ.y * softplus_f(NL.y) * NSCALE;
        G.z += NZ.z * softplus_f(NL.z) * NSCALE;
        G.w += NZ.w * softplus_f(NL.w) * NSCALE;
        *(float4*)(lgf + pr * 132 + c4 * 4) = G;
        *(float4*)(out_logits + (size_t)n1 * NE + c4 * 4) = G;
    }
    __syncthreads();

    // ---- phase2: per-row top-2 + softmax; waves 0..3, 8 lanes/row ----
    if (w < 4) {
        const int g2   = l >> 3;           // row within wave's 8-row group
        const int c    = l & 7;            // expert chunk of 8
        const int row2 = w * 8 + g2;
        const int n2   = row0 + row2;

        float mv[8];
        {
            const float4* mr = (const float4*)(lgf + row2 * 132 + c * 8);
            float4 m0 = mr[0], m1 = mr[1];
            mv[0]=m0.x; mv[1]=m0.y; mv[2]=m0.z; mv[3]=m0.w;
            mv[4]=m1.x; mv[5]=m1.y; mv[6]=m1.z; mv[7]=m1.w;
        }
        float v0 = -INFINITY, v1 = -INFINITY;
        int i0 = 0, i1 = 0;
        #pragma unroll
        for (int j = 0; j < 8; ++j) {
            float v = mv[j]; int e = c * 8 + j;
            if (v > v0) { v1 = v0; i1 = i0; v0 = v; i0 = e; }
            else if (v > v1) { v1 = v; i1 = e; }
        }
        #pragma unroll
        for (int m = 1; m <= 4; m <<= 1) {
            float ov0 = __shfl_xor(v0, m), ov1 = __shfl_xor(v1, m);
            int   oi0 = __shfl_xor(i0, m), oi1 = __shfl_xor(i1, m);
            if (ov0 > v0) {
                bool keep = (v0 > ov1);
                v1 = keep ? v0 : ov1; i1 = keep ? i0 : oi1;
                v0 = ov0; i0 = oi0;
            } else if (ov0 > v1) {
                v1 = ov0; i1 = oi0;
            }
        }
        const int srcl = l & 56;
        v0 = __shfl(v0, srcl); i0 = __shfl(i0, srcl);
        v1 = __shfl(v1, srcl); i1 = __shfl(i1, srcl);

        float se = 0.0f;
        #pragma unroll
        for (int j = 0; j < 8; ++j) se += expf(mv[j] - v0);
        se += __shfl_xor(se, 1); se += __shfl_xor(se, 2); se += __shfl_xor(se, 4);
        float inv_se = 1.0f / se;

        float t  = expf(v1 - v0);
        float w0 = 1.0f / (1.0f + t);
        float w1 = t * w0;

        float pr[8], wt[8];
        #pragma unroll
        for (int j = 0; j < 8; ++j) {
            int e = c * 8 + j;
            pr[j] = expf(mv[j] - v0) * inv_se;
            wt[j] = (e == i0) ? w0 : ((e == i1) ? w1 : 0.0f);
        }
        *(float4*)(out_probs + (size_t)n2 * NE + c * 8)     = make_float4(pr[0], pr[1], pr[2], pr[3]);
        *(float4*)(out_probs + (size_t)n2 * NE + c * 8 + 4) = make_float4(pr[4], pr[5], pr[6], pr[7]);
        *(float4*)(out_w + (size_t)n2 * NE + c * 8)         = make_float4(wt[0], wt[1], wt[2], wt[3]);
        *(float4*)(out_w + (size_t)n2 * NE + c * 8 + 4)     = make_float4(wt[4], wt[5], wt[6], wt[7]);
        if (c == 0) {
            *(float2*)(out_idx + (size_t)n2 * 2) = make_float2((float)i0, (float)i1);
        }
    }
}

extern "C" void kernel_launch(void* const* d_in, const int* in_sizes, int n_in,
                              void* d_out, int out_size, void* d_ws, size_t ws_size,
                              hipStream_t stream) {
    (void)in_sizes; (void)n_in; (void)ws_size; (void)out_size;
    const float* x     = (const float*)d_in[0];
    const float* Wg    = (const float*)d_in[1];
    const float* Wn    = (const float*)d_in[2];
    const float* noise = (const float*)d_in[3];
    float* out        = (float*)d_out;
    float* out_w      = out;
    float* out_idx    = out + (size_t)NROWS * NE;
    float* out_logits = out_idx + (size_t)NROWS * 2;
    float* out_probs  = out_logits + (size_t)NROWS * NE;
    f16* wfrag = (f16*)d_ws;   // 1 MB

    wprep_kernel<<<128, 256, 0, stream>>>(Wg, Wn, wfrag);
    gemm_gating<<<NROWS / BM, 512, 0, stream>>>(
        x, wfrag, noise, out_w, out_idx, out_logits, out_probs);
}